// Round 1
// baseline (5173.058 us; speedup 1.0000x reference)
//
#include <hip/hip_runtime.h>
#include <hip/hip_bf16.h>
#include <math.h>

typedef unsigned short u16;
typedef __attribute__((ext_vector_type(8))) short bf16x8;
typedef __attribute__((ext_vector_type(4))) float f32x4;
typedef __attribute__((address_space(1))) unsigned int gu32;
typedef __attribute__((address_space(3))) unsigned int lu32;

#define DD 1024
#define PP 32
#define BM 128
#define BN 128
#define BKT 64

__device__ __forceinline__ u16 f2bf(float f) {
  unsigned u = __float_as_uint(f);
  unsigned r = u + 0x7fffu + ((u >> 16) & 1u);
  return (u16)(r >> 16);
}
__device__ __forceinline__ float bf2f(u16 h) {
  return __uint_as_float(((unsigned)h) << 16);
}

// ---------------- conversions ----------------
// x [B,1024] f32 -> bf16 into left half of combined [B,2048]
__global__ __launch_bounds__(256) void k_convert_x(const float* __restrict__ x,
                                                   u16* __restrict__ comb, int n4) {
  for (int i = blockIdx.x * 256 + threadIdx.x; i < n4; i += gridDim.x * 256) {
    float4 v = ((const float4*)x)[i];
    int row = i >> 8;        // 256 float4 per row
    int c4  = i & 255;
    ushort4 o;
    o.x = f2bf(v.x); o.y = f2bf(v.y); o.z = f2bf(v.z); o.w = f2bf(v.w);
    *(ushort4*)(comb + ((size_t)row << 11) + (c4 << 2)) = o;
  }
}

__global__ __launch_bounds__(256) void k_convert(const float* __restrict__ in,
                                                 u16* __restrict__ out, int n4) {
  for (int i = blockIdx.x * 256 + threadIdx.x; i < n4; i += gridDim.x * 256) {
    float4 v = ((const float4*)in)[i];
    ushort4 o;
    o.x = f2bf(v.x); o.y = f2bf(v.y); o.z = f2bf(v.z); o.w = f2bf(v.w);
    ((ushort4*)out)[i] = o;
  }
}

// prototypes [32,1024] f32 -> row-l2-normalized bf16
__global__ __launch_bounds__(256) void k_proto_prep(const float* __restrict__ protos,
                                                    u16* __restrict__ pb) {
  __shared__ float sb[4];
  int row = blockIdx.x, tid = threadIdx.x;
  float4 v = ((const float4*)(protos + row * DD))[tid];
  float q = v.x * v.x + v.y * v.y + v.z * v.z + v.w * v.w;
#pragma unroll
  for (int off = 32; off; off >>= 1) q += __shfl_xor(q, off);
  if ((tid & 63) == 0) sb[tid >> 6] = q;
  __syncthreads();
  q = sb[0] + sb[1] + sb[2] + sb[3];
  float inv = 1.0f / fmaxf(sqrtf(q), 1e-12f);
  ushort4 o;
  o.x = f2bf(v.x * inv); o.y = f2bf(v.y * inv); o.z = f2bf(v.z * inv); o.w = f2bf(v.w * inv);
  ((ushort4*)(pb + row * DD))[tid] = o;
}

// ---------------- bf16 GEMM, B^T layout: C[m,n] = sum_k A[m,k]*W[n,k] ----------------
// EPI 0: C = bf16(acc + bias[n])              (out: u16*, ldc)
// EPI 1: C = gelu(acc + bias[n]) + resid[m,n] (out: float*, ldc)
template <int EPI>
__global__ __launch_bounds__(256) void k_gemm(const u16* __restrict__ A, int lda,
                                              const u16* __restrict__ Bm,
                                              const float* __restrict__ bias,
                                              const float* __restrict__ resid,
                                              void* __restrict__ Cout, int ldc, int K) {
  __shared__ u16 As[BM * BKT];
  __shared__ u16 Bs[BN * BKT];
  const int tid = threadIdx.x;
  const int w = tid >> 6, lane = tid & 63;
  const int wm = w >> 1, wn = w & 1;
  const int bm = blockIdx.y, bn = blockIdx.x;

  f32x4 zero = {0.f, 0.f, 0.f, 0.f};
  f32x4 acc[4][4];
#pragma unroll
  for (int i = 0; i < 4; ++i)
#pragma unroll
    for (int j = 0; j < 4; ++j) acc[i][j] = zero;

  const u16* Ag = A + (size_t)bm * BM * lda;
  const u16* Bg = Bm + (size_t)bn * BN * K;

  for (int k0 = 0; k0 < K; k0 += BKT) {
#pragma unroll
    for (int r = 0; r < 4; ++r) {
      int lt = r * 256 + tid;
      int row = lt >> 3, col = (lt & 7) << 3;
      __builtin_amdgcn_global_load_lds(
          (gu32*)(Ag + (size_t)row * lda + k0 + col),
          (lu32*)(As + (size_t)(r * 256 + (w << 6)) * 8), 16, 0, 0);
    }
#pragma unroll
    for (int r = 0; r < 4; ++r) {
      int lt = r * 256 + tid;
      int row = lt >> 3, col = (lt & 7) << 3;
      __builtin_amdgcn_global_load_lds(
          (gu32*)(Bg + (size_t)row * K + k0 + col),
          (lu32*)(Bs + (size_t)(r * 256 + (w << 6)) * 8), 16, 0, 0);
    }
    __syncthreads();
#pragma unroll
    for (int kk = 0; kk < 2; ++kk) {
      bf16x8 af[4], bfr[4];
      const int krow = kk * 32 + (lane >> 4) * 8;
#pragma unroll
      for (int mi = 0; mi < 4; ++mi)
        af[mi] = *(const bf16x8*)(As + (wm * 64 + mi * 16 + (lane & 15)) * BKT + krow);
#pragma unroll
      for (int ni = 0; ni < 4; ++ni)
        bfr[ni] = *(const bf16x8*)(Bs + (wn * 64 + ni * 16 + (lane & 15)) * BKT + krow);
#pragma unroll
      for (int mi = 0; mi < 4; ++mi)
#pragma unroll
        for (int ni = 0; ni < 4; ++ni)
          acc[mi][ni] = __builtin_amdgcn_mfma_f32_16x16x32_bf16(af[mi], bfr[ni], acc[mi][ni], 0, 0, 0);
    }
    __syncthreads();
  }

  // epilogue: C/D layout col = lane&15, row = (lane>>4)*4 + r
  const int rbase = (lane >> 4) * 4;
  const int cl = lane & 15;
#pragma unroll
  for (int mi = 0; mi < 4; ++mi) {
#pragma unroll
    for (int ni = 0; ni < 4; ++ni) {
      int gcol = bn * BN + wn * 64 + ni * 16 + cl;
      float bv = bias[gcol];
#pragma unroll
      for (int r = 0; r < 4; ++r) {
        int grow = bm * BM + wm * 64 + mi * 16 + rbase + r;
        float v = acc[mi][ni][r] + bv;
        if (EPI == 0) {
          ((u16*)Cout)[(size_t)grow * ldc + gcol] = f2bf(v);
        } else {
          float g = 0.5f * v * (1.0f + erff(v * 0.70710678118654752f));
          float y = g + resid[(size_t)grow * ldc + gcol];
          ((float*)Cout)[(size_t)grow * ldc + gcol] = y;
        }
      }
    }
  }
}

// ---------------- per-row: l2norm(h) @ proto^T -> softmax -> attn @ proto ----------------
// one wave per row; h row in registers (16 f32/lane); protos in LDS (bf16, 64 KB)
__global__ __launch_bounds__(256) void k_proto_attn(const u16* __restrict__ h,
                                                    const u16* __restrict__ pb,
                                                    u16* __restrict__ comb) {
  __shared__ u16 pl[PP * DD];
  const int tid = threadIdx.x;
  for (int i = tid; i < PP * DD / 8; i += 256)
    ((int4*)pl)[i] = ((const int4*)pb)[i];
  __syncthreads();
  const int w = tid >> 6, lane = tid & 63;
  int row = blockIdx.x * 32 + w * 8;
  for (int ri = 0; ri < 8; ++ri, ++row) {
    const u16* hr = h + ((size_t)row << 10) + lane * 16;
    float hv[16];
    {
      bf16x8 a = *(const bf16x8*)hr;
      bf16x8 b = *(const bf16x8*)(hr + 8);
#pragma unroll
      for (int j = 0; j < 8; ++j) { hv[j] = bf2f((u16)a[j]); hv[8 + j] = bf2f((u16)b[j]); }
    }
    float ss = 0.f;
#pragma unroll
    for (int j = 0; j < 16; ++j) ss += hv[j] * hv[j];
#pragma unroll
    for (int off = 32; off; off >>= 1) ss += __shfl_xor(ss, off);

    float dots[PP];
#pragma unroll
    for (int p = 0; p < PP; ++p) {
      const u16* pp = pl + p * DD + lane * 16;
      bf16x8 a = *(const bf16x8*)pp;
      bf16x8 b = *(const bf16x8*)(pp + 8);
      float d = 0.f;
#pragma unroll
      for (int j = 0; j < 8; ++j) d += hv[j] * bf2f((u16)a[j]);
#pragma unroll
      for (int j = 0; j < 8; ++j) d += hv[8 + j] * bf2f((u16)b[j]);
#pragma unroll
      for (int off = 32; off; off >>= 1) d += __shfl_xor(d, off);
      dots[p] = d;
    }
    // sim = dot / max(||h||,eps) / TEMP ;  TEMP=0.1
    float inv = 10.0f / fmaxf(sqrtf(ss), 1e-12f);
    float m = -1e30f;
#pragma unroll
    for (int p = 0; p < PP; ++p) { dots[p] *= inv; m = fmaxf(m, dots[p]); }
    float s = 0.f;
#pragma unroll
    for (int p = 0; p < PP; ++p) { dots[p] = expf(dots[p] - m); s += dots[p]; }
    float rs = 1.0f / s;
    float rv[16];
#pragma unroll
    for (int j = 0; j < 16; ++j) rv[j] = 0.f;
#pragma unroll
    for (int p = 0; p < PP; ++p) {
      const u16* pp = pl + p * DD + lane * 16;
      bf16x8 a = *(const bf16x8*)pp;
      bf16x8 b = *(const bf16x8*)(pp + 8);
      float ap = dots[p] * rs;
#pragma unroll
      for (int j = 0; j < 8; ++j) { rv[j] += ap * bf2f((u16)a[j]); rv[8 + j] += ap * bf2f((u16)b[j]); }
    }
    u16* cr = comb + ((size_t)row << 11) + 1024 + lane * 16;
#pragma unroll
    for (int t = 0; t < 4; ++t) {
      ushort4 o4;
      o4.x = f2bf(rv[t * 4 + 0]); o4.y = f2bf(rv[t * 4 + 1]);
      o4.z = f2bf(rv[t * 4 + 2]); o4.w = f2bf(rv[t * 4 + 3]);
      *(ushort4*)(cr + t * 4) = o4;
    }
  }
}

// ---------------- in-place LayerNorm over rows of 1024 ----------------
__global__ __launch_bounds__(256) void k_ln(float* __restrict__ io,
                                            const float* __restrict__ gamma,
                                            const float* __restrict__ beta) {
  __shared__ float sb[8];
  size_t row = blockIdx.x;
  float4* rp = (float4*)(io + (row << 10));
  int tid = threadIdx.x;
  float4 v = rp[tid];
  float s = v.x + v.y + v.z + v.w;
  float q = v.x * v.x + v.y * v.y + v.z * v.z + v.w * v.w;
#pragma unroll
  for (int off = 32; off; off >>= 1) { s += __shfl_xor(s, off); q += __shfl_xor(q, off); }
  if ((tid & 63) == 0) { sb[tid >> 6] = s; sb[4 + (tid >> 6)] = q; }
  __syncthreads();
  s = sb[0] + sb[1] + sb[2] + sb[3];
  q = sb[4] + sb[5] + sb[6] + sb[7];
  float mu = s * (1.f / 1024.f);
  float var = q * (1.f / 1024.f) - mu * mu;
  float rstd = rsqrtf(var + 1e-5f);
  float4 g = ((const float4*)gamma)[tid];
  float4 b = ((const float4*)beta)[tid];
  v.x = (v.x - mu) * rstd * g.x + b.x;
  v.y = (v.y - mu) * rstd * g.y + b.y;
  v.z = (v.z - mu) * rstd * g.z + b.z;
  v.w = (v.w - mu) * rstd * g.w + b.w;
  rp[tid] = v;
}

extern "C" void kernel_launch(void* const* d_in, const int* in_sizes, int n_in,
                              void* d_out, int out_size, void* d_ws, size_t ws_size,
                              hipStream_t stream) {
  const float* x      = (const float*)d_in[0];
  const float* Wi     = (const float*)d_in[1];
  const float* bi     = (const float*)d_in[2];
  const float* Wo     = (const float*)d_in[3];
  const float* bo     = (const float*)d_in[4];
  const float* gamma  = (const float*)d_in[5];
  const float* beta   = (const float*)d_in[6];
  const float* protos = (const float*)d_in[7];
  const int Brows = in_sizes[0] / DD;  // 65536

  // workspace layout (bf16)
  u16* comb = (u16*)d_ws;                        // [B, 2048]
  u16* WiB  = comb + (size_t)Brows * 2048;       // [1024, 1024]
  u16* WoB  = WiB + (size_t)1024 * 1024;         // [1024, 2048]
  u16* pb   = WoB + (size_t)1024 * 2048;         // [32, 1024]
  // h (bf16 [B,1024]) lives in d_out's storage; dead before GEMM2 writes f32 there
  u16* hbuf = (u16*)d_out;

  k_convert_x<<<4096, 256, 0, stream>>>(x, comb, Brows * 256);
  k_convert<<<1024, 256, 0, stream>>>(Wi, WiB, 1024 * 1024 / 4);
  k_convert<<<2048, 256, 0, stream>>>(Wo, WoB, 1024 * 2048 / 4);
  k_proto_prep<<<PP, 256, 0, stream>>>(protos, pb);

  // h = x @ Wi^T + bi   (A = combined left half, lda=2048)
  k_gemm<0><<<dim3(8, Brows / BM), 256, 0, stream>>>(comb, 2048, WiB, bi, nullptr,
                                                     (void*)hbuf, DD, DD);
  // softmax-attention over prototypes -> combined right half
  k_proto_attn<<<Brows / 32, 256, 0, stream>>>(hbuf, pb, comb);
  // y = gelu(combined @ Wo^T + bo) + x  -> d_out (f32)
  k_gemm<1><<<dim3(8, Brows / BM), 256, 0, stream>>>(comb, 2048, WoB, bo, x,
                                                     d_out, DD, 2 * DD);
  // in-place LayerNorm
  k_ln<<<Brows, 256, 0, stream>>>((float*)d_out, gamma, beta);
}

// Round 3
// 1223.413 us; speedup vs baseline: 4.2284x; 4.2284x over previous
//
#include <hip/hip_runtime.h>
#include <hip/hip_bf16.h>
#include <math.h>

typedef unsigned short u16;
typedef __attribute__((ext_vector_type(8))) short bf16x8;
typedef __attribute__((ext_vector_type(4))) float f32x4;
typedef __attribute__((address_space(1))) unsigned int gu32;
typedef __attribute__((address_space(3))) unsigned int lu32;

#define DD 1024
#define PP 32
#define BM 128
#define BN 128
#define BKT 64

__device__ __forceinline__ u16 f2bf(float f) {
  unsigned u = __float_as_uint(f);
  unsigned r = u + 0x7fffu + ((u >> 16) & 1u);
  return (u16)(r >> 16);
}
__device__ __forceinline__ float bf2f(u16 h) {
  return __uint_as_float(((unsigned)h) << 16);
}

// ---------------- conversions ----------------
// x [B,1024] f32 -> bf16 into left half of combined [B,2048]
__global__ __launch_bounds__(256) void k_convert_x(const float* __restrict__ x,
                                                   u16* __restrict__ comb, int n4) {
  for (int i = blockIdx.x * 256 + threadIdx.x; i < n4; i += gridDim.x * 256) {
    float4 v = ((const float4*)x)[i];
    int row = i >> 8;        // 256 float4 per row
    int c4  = i & 255;
    ushort4 o;
    o.x = f2bf(v.x); o.y = f2bf(v.y); o.z = f2bf(v.z); o.w = f2bf(v.w);
    *(ushort4*)(comb + ((size_t)row << 11) + (c4 << 2)) = o;
  }
}

__global__ __launch_bounds__(256) void k_convert(const float* __restrict__ in,
                                                 u16* __restrict__ out, int n4) {
  for (int i = blockIdx.x * 256 + threadIdx.x; i < n4; i += gridDim.x * 256) {
    float4 v = ((const float4*)in)[i];
    ushort4 o;
    o.x = f2bf(v.x); o.y = f2bf(v.y); o.z = f2bf(v.z); o.w = f2bf(v.w);
    ((ushort4*)out)[i] = o;
  }
}

// prototypes [32,1024] f32 -> row-l2-normalized bf16 (for sim)
__global__ __launch_bounds__(256) void k_proto_prep(const float* __restrict__ protos,
                                                    u16* __restrict__ pb) {
  __shared__ float sb[4];
  int row = blockIdx.x, tid = threadIdx.x;
  float4 v = ((const float4*)(protos + row * DD))[tid];
  float q = v.x * v.x + v.y * v.y + v.z * v.z + v.w * v.w;
#pragma unroll
  for (int off = 32; off; off >>= 1) q += __shfl_xor(q, off);
  if ((tid & 63) == 0) sb[tid >> 6] = q;
  __syncthreads();
  q = sb[0] + sb[1] + sb[2] + sb[3];
  float inv = 1.0f / fmaxf(sqrtf(q), 1e-12f);
  ushort4 o;
  o.x = f2bf(v.x * inv); o.y = f2bf(v.y * inv); o.z = f2bf(v.z * inv); o.w = f2bf(v.w * inv);
  ((ushort4*)(pb + row * DD))[tid] = o;
}

// prototypes [32,1024] f32 -> transposed bf16 [1024,32] (raw values, for retrieved)
__global__ __launch_bounds__(256) void k_protoT(const float* __restrict__ protos,
                                                u16* __restrict__ pbT) {
  int i = blockIdx.x * 256 + threadIdx.x;  // 32768 total
  if (i < DD * PP) {
    int p = i & 31, d = i >> 5;
    pbT[i] = f2bf(protos[p * DD + d]);
  }
}

// ---------------- bf16 GEMM, B^T layout: C[m,n] = sum_k A[m,k]*W[n,k] ----------------
// EPI 0: C = bf16(acc + bias[n])              (out: u16*, ldc)
// EPI 1: C = gelu(acc + bias[n]) + resid[m,n] (out: float*, ldc)
template <int EPI>
__global__ __launch_bounds__(256) void k_gemm(const u16* __restrict__ A, int lda,
                                              const u16* __restrict__ Bm,
                                              const float* __restrict__ bias,
                                              const float* __restrict__ resid,
                                              void* __restrict__ Cout, int ldc, int K) {
  __shared__ u16 As[BM * BKT];
  __shared__ u16 Bs[BN * BKT];
  const int tid = threadIdx.x;
  const int w = tid >> 6, lane = tid & 63;
  const int wm = w >> 1, wn = w & 1;
  const int bm = blockIdx.y, bn = blockIdx.x;

  f32x4 zero = {0.f, 0.f, 0.f, 0.f};
  f32x4 acc[4][4];
#pragma unroll
  for (int i = 0; i < 4; ++i)
#pragma unroll
    for (int j = 0; j < 4; ++j) acc[i][j] = zero;

  const u16* Ag = A + (size_t)bm * BM * lda;
  const u16* Bg = Bm + (size_t)bn * BN * K;

  for (int k0 = 0; k0 < K; k0 += BKT) {
#pragma unroll
    for (int r = 0; r < 4; ++r) {
      int lt = r * 256 + tid;
      int row = lt >> 3, col = (lt & 7) << 3;
      __builtin_amdgcn_global_load_lds(
          (gu32*)(Ag + (size_t)row * lda + k0 + col),
          (lu32*)(As + (size_t)(r * 256 + (w << 6)) * 8), 16, 0, 0);
    }
#pragma unroll
    for (int r = 0; r < 4; ++r) {
      int lt = r * 256 + tid;
      int row = lt >> 3, col = (lt & 7) << 3;
      __builtin_amdgcn_global_load_lds(
          (gu32*)(Bg + (size_t)row * K + k0 + col),
          (lu32*)(Bs + (size_t)(r * 256 + (w << 6)) * 8), 16, 0, 0);
    }
    __syncthreads();
#pragma unroll
    for (int kk = 0; kk < 2; ++kk) {
      bf16x8 af[4], bfr[4];
      const int krow = kk * 32 + (lane >> 4) * 8;
#pragma unroll
      for (int mi = 0; mi < 4; ++mi)
        af[mi] = *(const bf16x8*)(As + (wm * 64 + mi * 16 + (lane & 15)) * BKT + krow);
#pragma unroll
      for (int ni = 0; ni < 4; ++ni)
        bfr[ni] = *(const bf16x8*)(Bs + (wn * 64 + ni * 16 + (lane & 15)) * BKT + krow);
#pragma unroll
      for (int mi = 0; mi < 4; ++mi)
#pragma unroll
        for (int ni = 0; ni < 4; ++ni)
          acc[mi][ni] = __builtin_amdgcn_mfma_f32_16x16x32_bf16(af[mi], bfr[ni], acc[mi][ni], 0, 0, 0);
    }
    __syncthreads();
  }

  // epilogue: C/D layout col = lane&15, row = (lane>>4)*4 + r
  const int rbase = (lane >> 4) * 4;
  const int cl = lane & 15;
#pragma unroll
  for (int mi = 0; mi < 4; ++mi) {
#pragma unroll
    for (int ni = 0; ni < 4; ++ni) {
      int gcol = bn * BN + wn * 64 + ni * 16 + cl;
      float bv = bias[gcol];
#pragma unroll
      for (int r = 0; r < 4; ++r) {
        int grow = bm * BM + wm * 64 + mi * 16 + rbase + r;
        float v = acc[mi][ni][r] + bv;
        if (EPI == 0) {
          ((u16*)Cout)[(size_t)grow * ldc + gcol] = f2bf(v);
        } else {
          float g = 0.5f * v * (1.0f + erff(v * 0.70710678118654752f));
          float y = g + resid[(size_t)grow * ldc + gcol];
          ((float*)Cout)[(size_t)grow * ldc + gcol] = y;
        }
      }
    }
  }
}

// ---------------- fused: sim (MFMA) -> softmax -> retrieved (MFMA) ----------------
// block = 4 waves, each wave owns 16 rows. grid = B/64.
// h [B,1024] bf16; pb [32,1024] bf16 normalized; pbT [1024,32] bf16 raw.
// writes retrieved bf16 into comb right half.
__global__ __launch_bounds__(256) void k_mid(const u16* __restrict__ h,
                                             const u16* __restrict__ pb,
                                             const u16* __restrict__ pbT,
                                             u16* __restrict__ comb) {
  __shared__ u16 attn_sm[4][16 * 32];
  const int tid = threadIdx.x;
  const int w = tid >> 6, lane = tid & 63;
  const int lm = lane & 15, lk = lane >> 4;
  const int row0 = blockIdx.x * 64 + w * 16;

  f32x4 zero = {0.f, 0.f, 0.f, 0.f};
  f32x4 acc0 = zero, acc1 = zero;
  float ss = 0.f;

  // sim = h @ pn^T   (C[m=row][n=proto]) ; also accumulate ||h||^2 from A-frags
  const u16* hrow = h + ((size_t)(row0 + lm) << 10) + lk * 8;
  const u16* pb0 = pb + (size_t)lm * DD + lk * 8;
  const u16* pb1 = pb + (size_t)(16 + lm) * DD + lk * 8;
#pragma unroll 4
  for (int k0 = 0; k0 < DD; k0 += 32) {
    bf16x8 af = *(const bf16x8*)(hrow + k0);
    bf16x8 b0 = *(const bf16x8*)(pb0 + k0);
    bf16x8 b1 = *(const bf16x8*)(pb1 + k0);
    acc0 = __builtin_amdgcn_mfma_f32_16x16x32_bf16(af, b0, acc0, 0, 0, 0);
    acc1 = __builtin_amdgcn_mfma_f32_16x16x32_bf16(af, b1, acc1, 0, 0, 0);
#pragma unroll
    for (int j = 0; j < 8; ++j) {
      float hv = bf2f((u16)af[j]);
      ss += hv * hv;
    }
  }
  // ss partial covers row lm, k in lk-slices: reduce across lk (xor 16, 32)
  ss += __shfl_xor(ss, 16);
  ss += __shfl_xor(ss, 32);
  // every lane now has ||h[row0+lm]||^2 ; inv = (1/TEMP)/max(||h||,eps)
  float inv = 10.0f / fmaxf(sqrtf(ss), 1e-12f);

  // softmax per row; row of acc[r] = (lk*4 + r), col = lm (+16 for acc1)
  float a0[4], a1[4];
#pragma unroll
  for (int r = 0; r < 4; ++r) {
    float invr = __shfl(inv, lk * 4 + r);  // inv for row (lk*4+r) lives in lane (lk*4+r)
    float s0 = acc0[r] * invr;
    float s1 = acc1[r] * invr;
    float mr = fmaxf(s0, s1);
#pragma unroll
    for (int off = 1; off < 16; off <<= 1) mr = fmaxf(mr, __shfl_xor(mr, off));
    float e0 = expf(s0 - mr);
    float e1 = expf(s1 - mr);
    float sum = e0 + e1;
#pragma unroll
    for (int off = 1; off < 16; off <<= 1) sum += __shfl_xor(sum, off);
    float rs = 1.0f / sum;
    a0[r] = e0 * rs;
    a1[r] = e1 * rs;
  }

  // bounce attn through LDS to reshape into B-operand frag (row-major [16 rows][32 protos])
  u16* as = attn_sm[w];
#pragma unroll
  for (int r = 0; r < 4; ++r) {
    as[(lk * 4 + r) * 32 + lm] = f2bf(a0[r]);
    as[(lk * 4 + r) * 32 + 16 + lm] = f2bf(a1[r]);
  }
  __syncthreads();
  // B'-frag: lane holds attn[row = lm][proto = lk*8 + j] — reused for all 64 dim-blocks
  bf16x8 battn = *(const bf16x8*)(as + lm * 32 + lk * 8);

  // retrieved^T: C'[dim][row] = pbT_frag (A: [dim][proto]) @ attn (B: [row][proto])
  u16* crow = comb + ((size_t)(row0 + lm) << 11) + DD;
#pragma unroll 4
  for (int d0 = 0; d0 < DD; d0 += 16) {
    bf16x8 ap = *(const bf16x8*)(pbT + (size_t)(d0 + lm) * PP + lk * 8);
    f32x4 rc = __builtin_amdgcn_mfma_f32_16x16x32_bf16(ap, battn, zero, 0, 0, 0);
    // lane holds dims d0 + lk*4 + r for row row0 + lm
    ushort4 o;
    o.x = f2bf(rc[0]); o.y = f2bf(rc[1]); o.z = f2bf(rc[2]); o.w = f2bf(rc[3]);
    *(ushort4*)(crow + d0 + lk * 4) = o;
  }
}

// ---------------- in-place LayerNorm over rows of 1024 ----------------
__global__ __launch_bounds__(256) void k_ln(float* __restrict__ io,
                                            const float* __restrict__ gamma,
                                            const float* __restrict__ beta) {
  __shared__ float sb[8];
  size_t row = blockIdx.x;
  float4* rp = (float4*)(io + (row << 10));
  int tid = threadIdx.x;
  float4 v = rp[tid];
  float s = v.x + v.y + v.z + v.w;
  float q = v.x * v.x + v.y * v.y + v.z * v.z + v.w * v.w;
#pragma unroll
  for (int off = 32; off; off >>= 1) { s += __shfl_xor(s, off); q += __shfl_xor(q, off); }
  if ((tid & 63) == 0) { sb[tid >> 6] = s; sb[4 + (tid >> 6)] = q; }
  __syncthreads();
  s = sb[0] + sb[1] + sb[2] + sb[3];
  q = sb[4] + sb[5] + sb[6] + sb[7];
  float mu = s * (1.f / 1024.f);
  float var = q * (1.f / 1024.f) - mu * mu;
  float rstd = rsqrtf(var + 1e-5f);
  float4 g = ((const float4*)gamma)[tid];
  float4 b = ((const float4*)beta)[tid];
  v.x = (v.x - mu) * rstd * g.x + b.x;
  v.y = (v.y - mu) * rstd * g.y + b.y;
  v.z = (v.z - mu) * rstd * g.z + b.z;
  v.w = (v.w - mu) * rstd * g.w + b.w;
  rp[tid] = v;
}

extern "C" void kernel_launch(void* const* d_in, const int* in_sizes, int n_in,
                              void* d_out, int out_size, void* d_ws, size_t ws_size,
                              hipStream_t stream) {
  const float* x      = (const float*)d_in[0];
  const float* Wi     = (const float*)d_in[1];
  const float* bi     = (const float*)d_in[2];
  const float* Wo     = (const float*)d_in[3];
  const float* bo     = (const float*)d_in[4];
  const float* gamma  = (const float*)d_in[5];
  const float* beta   = (const float*)d_in[6];
  const float* protos = (const float*)d_in[7];
  const int Brows = in_sizes[0] / DD;  // 65536

  // workspace layout (bf16)
  u16* comb = (u16*)d_ws;                        // [B, 2048]
  u16* WiB  = comb + (size_t)Brows * 2048;       // [1024, 1024]
  u16* WoB  = WiB + (size_t)1024 * 1024;         // [1024, 2048]
  u16* pb   = WoB + (size_t)1024 * 2048;         // [32, 1024] normalized
  u16* pbT  = pb + (size_t)PP * DD;              // [1024, 32] raw transposed
  // h (bf16 [B,1024]) lives in d_out's storage; dead before GEMM2 writes f32 there
  u16* hbuf = (u16*)d_out;

  k_convert_x<<<4096, 256, 0, stream>>>(x, comb, Brows * 256);
  k_convert<<<1024, 256, 0, stream>>>(Wi, WiB, 1024 * 1024 / 4);
  k_convert<<<2048, 256, 0, stream>>>(Wo, WoB, 1024 * 2048 / 4);
  k_proto_prep<<<PP, 256, 0, stream>>>(protos, pb);
  k_protoT<<<(DD * PP + 255) / 256, 256, 0, stream>>>(protos, pbT);

  // h = x @ Wi^T + bi   (A = combined left half, lda=2048)
  k_gemm<0><<<dim3(8, Brows / BM), 256, 0, stream>>>(comb, 2048, WiB, bi, nullptr,
                                                     (void*)hbuf, DD, DD);
  // fused sim -> softmax -> retrieved into combined right half
  k_mid<<<Brows / 64, 256, 0, stream>>>(hbuf, pb, pbT, comb);
  // y = gelu(combined @ Wo^T + bo) + x  -> d_out (f32)   (N=1024 -> 8 col-blocks, ldc=DD)
  k_gemm<1><<<dim3(8, Brows / BM), 256, 0, stream>>>(comb, 2048, WoB, bo, x,
                                                     d_out, DD, 2 * DD);
  // in-place LayerNorm
  k_ln<<<Brows, 256, 0, stream>>>((float*)d_out, gamma, beta);
}

// Round 4
// 1001.579 us; speedup vs baseline: 5.1649x; 1.2215x over previous
//
#include <hip/hip_runtime.h>
#include <hip/hip_bf16.h>
#include <math.h>

typedef unsigned short u16;
typedef __attribute__((ext_vector_type(8))) short bf16x8;
typedef __attribute__((ext_vector_type(4))) float f32x4;
typedef __attribute__((address_space(1))) unsigned int gu32;
typedef __attribute__((address_space(3))) unsigned int lu32;

#define DD 1024
#define PP 32

__device__ __forceinline__ u16 f2bf(float f) {
  unsigned u = __float_as_uint(f);
  unsigned r = u + 0x7fffu + ((u >> 16) & 1u);
  return (u16)(r >> 16);
}
__device__ __forceinline__ float bf2f(u16 h) {
  return __uint_as_float(((unsigned)h) << 16);
}

// ---------------- conversions ----------------
__global__ __launch_bounds__(256) void k_convert_x(const float* __restrict__ x,
                                                   u16* __restrict__ comb, int n4) {
  for (int i = blockIdx.x * 256 + threadIdx.x; i < n4; i += gridDim.x * 256) {
    float4 v = ((const float4*)x)[i];
    int row = i >> 8;
    int c4  = i & 255;
    ushort4 o;
    o.x = f2bf(v.x); o.y = f2bf(v.y); o.z = f2bf(v.z); o.w = f2bf(v.w);
    *(ushort4*)(comb + ((size_t)row << 11) + (c4 << 2)) = o;
  }
}

__global__ __launch_bounds__(256) void k_convert(const float* __restrict__ in,
                                                 u16* __restrict__ out, int n4) {
  for (int i = blockIdx.x * 256 + threadIdx.x; i < n4; i += gridDim.x * 256) {
    float4 v = ((const float4*)in)[i];
    ushort4 o;
    o.x = f2bf(v.x); o.y = f2bf(v.y); o.z = f2bf(v.z); o.w = f2bf(v.w);
    ((ushort4*)out)[i] = o;
  }
}

__global__ __launch_bounds__(256) void k_proto_prep(const float* __restrict__ protos,
                                                    u16* __restrict__ pb) {
  __shared__ float sb[4];
  int row = blockIdx.x, tid = threadIdx.x;
  float4 v = ((const float4*)(protos + row * DD))[tid];
  float q = v.x * v.x + v.y * v.y + v.z * v.z + v.w * v.w;
#pragma unroll
  for (int off = 32; off; off >>= 1) q += __shfl_xor(q, off);
  if ((tid & 63) == 0) sb[tid >> 6] = q;
  __syncthreads();
  q = sb[0] + sb[1] + sb[2] + sb[3];
  float inv = 1.0f / fmaxf(sqrtf(q), 1e-12f);
  ushort4 o;
  o.x = f2bf(v.x * inv); o.y = f2bf(v.y * inv); o.z = f2bf(v.z * inv); o.w = f2bf(v.w * inv);
  ((ushort4*)(pb + row * DD))[tid] = o;
}

__global__ __launch_bounds__(256) void k_protoT(const float* __restrict__ protos,
                                                u16* __restrict__ pbT) {
  int i = blockIdx.x * 256 + threadIdx.x;
  if (i < DD * PP) {
    int p = i & 31, d = i >> 5;
    pbT[i] = f2bf(protos[p * DD + d]);
  }
}

// ---------------- 256x256 8-phase bf16 GEMM (B^T layout) ----------------
// C[m,n] = sum_k A[m,k] * Bm[n,k]
// EPI 0: C = bf16(acc + bias[n])               -> (u16*)Cout, ldc
// EPI 1: C = gelu(acc + bias[n]) + resid[m,n]  -> (float*)Cout, ldc  (resid bf16, stride 2048)
#define GLL(gsrc, ldst) __builtin_amdgcn_global_load_lds((gu32*)(gsrc), (lu32*)(ldst), 16, 0, 0)

template <int EPI>
__global__ __launch_bounds__(512, 2) void k_gemm8(const u16* __restrict__ A, int lda,
                                                  const u16* __restrict__ Bm,
                                                  const float* __restrict__ bias,
                                                  const u16* __restrict__ residb,
                                                  void* __restrict__ Cout, int ldc,
                                                  int K, int nbn) {
  __shared__ u16 Als[2][256 * 64];
  __shared__ u16 Bls[2][256 * 64];
  const int tid = threadIdx.x;
  const int wid = tid >> 6, lane = tid & 63;
  const int wm = wid >> 2, wn = wid & 3;
  const int lm = lane & 15, lk = lane >> 4;
  const int NT = K >> 6;

  // XCD chunked swizzle: blocks sharing an A-tile land on the same XCD, adjacent in time
  int g = blockIdx.x;
  int cpx = gridDim.x >> 3;
  int lin = (g & 7) * cpx + (g >> 3);
  int bn = lin % nbn, bm = lin / nbn;
  const size_t bmBase = (size_t)bm * 256;
  const size_t bnBase = (size_t)bn * 256;

  f32x4 acc[8][4];
#pragma unroll
  for (int i = 0; i < 8; ++i)
#pragma unroll
    for (int j = 0; j < 4; ++j) acc[i][j] = (f32x4){0.f, 0.f, 0.f, 0.f};

  bf16x8 a[4][2], b[2][2];

  // stage one A half (mh): rows {mh*64..+63} and {128+mh*64..+63}, 2 instrs x 8KB
#define STAGE_A(bufv, kt, mh) do {                                              \
    int arow = (mh) * 64 + wid * 8 + (lane >> 3);                               \
    int acol = ((lane & 7) << 3) + (kt) * 64;                                   \
    GLL(A + (bmBase + arow) * lda + acol, &Als[bufv][((mh) * 64 + wid * 8) * 64]);       \
    GLL(A + (bmBase + 128 + arow) * lda + acol, &Als[bufv][(128 + (mh) * 64 + wid * 8) * 64]); \
  } while (0)

  // stage one B half (nh): n-rows {b*64 + nh*32 .. +31 : b=0..3}, 2 instrs x 8KB
#define STAGE_B(bufv, kt, nh) do {                                              \
    int br0 = ((wid >> 2) << 6) + (nh) * 32 + ((wid & 3) << 3);                 \
    int bcol = ((lane & 7) << 3) + (kt) * 64;                                   \
    GLL(Bm + (bnBase + br0 + (lane >> 3)) * (size_t)K + bcol, &Bls[bufv][br0 * 64]);       \
    GLL(Bm + (bnBase + 128 + br0 + (lane >> 3)) * (size_t)K + bcol, &Bls[bufv][(128 + br0) * 64]); \
  } while (0)

#define LOAD_A(bufv, mh) do {                                                   \
    _Pragma("unroll") for (int mi2 = 0; mi2 < 4; ++mi2) {                       \
      int row = wm * 128 + (mh) * 64 + mi2 * 16 + lm;                           \
      _Pragma("unroll") for (int kk = 0; kk < 2; ++kk)                          \
        a[mi2][kk] = *(const bf16x8*)&Als[bufv][row * 64 + kk * 32 + lk * 8];   \
    }                                                                           \
  } while (0)

#define LOAD_B(bufv, nh) do {                                                   \
    _Pragma("unroll") for (int ni2 = 0; ni2 < 2; ++ni2) {                       \
      int row = wn * 64 + (nh) * 32 + ni2 * 16 + lm;                            \
      _Pragma("unroll") for (int kk = 0; kk < 2; ++kk)                          \
        b[ni2][kk] = *(const bf16x8*)&Bls[bufv][row * 64 + kk * 32 + lk * 8];   \
    }                                                                           \
  } while (0)

#define WAITLGKM do { asm volatile("s_waitcnt lgkmcnt(0)" ::: "memory");        \
    __builtin_amdgcn_sched_barrier(0); } while (0)
#define BARRIER __builtin_amdgcn_s_barrier()

#define MFMA_Q(mh, nh) do {                                                     \
    __builtin_amdgcn_s_setprio(1);                                              \
    _Pragma("unroll") for (int mi2 = 0; mi2 < 4; ++mi2)                         \
    _Pragma("unroll") for (int ni2 = 0; ni2 < 2; ++ni2)                         \
    _Pragma("unroll") for (int kk = 0; kk < 2; ++kk)                            \
      acc[(mh) * 4 + mi2][(nh) * 2 + ni2] = __builtin_amdgcn_mfma_f32_16x16x32_bf16( \
          a[mi2][kk], b[ni2][kk], acc[(mh) * 4 + mi2][(nh) * 2 + ni2], 0, 0, 0); \
    __builtin_amdgcn_s_setprio(0);                                              \
  } while (0)

  // prologue: tile0 fully (4 halves) + tile1 A0,B1,A1 (3 halves) = 14 loads
  STAGE_A(0, 0, 0); STAGE_B(0, 0, 0); STAGE_A(0, 0, 1); STAGE_B(0, 0, 1);
  STAGE_A(1, 1, 0); STAGE_B(1, 1, 1); STAGE_A(1, 1, 1);
  asm volatile("s_waitcnt vmcnt(6)" ::: "memory");  // tile0 complete; 3 halves in flight
  BARRIER;

#define PHASE1(T, BUF) do {                                                     \
    LOAD_A(BUF, 0); LOAD_B(BUF, 0);                                             \
    if ((T) + 1 < NT) STAGE_B(((T) + 1) & 1, (T) + 1, 0);                       \
    BARRIER; WAITLGKM; MFMA_Q(0, 0); BARRIER;                                   \
  } while (0)
#define PHASE2(T, BUF) do {                                                     \
    LOAD_B(BUF, 1);                                                             \
    if ((T) + 2 < NT) STAGE_A(BUF, (T) + 2, 0);                                 \
    BARRIER; WAITLGKM; MFMA_Q(0, 1); BARRIER;                                   \
  } while (0)
#define PHASE3(T, BUF) do {                                                     \
    LOAD_A(BUF, 1);                                                             \
    if ((T) + 2 < NT) STAGE_B(BUF, (T) + 2, 1);                                 \
    BARRIER; WAITLGKM; MFMA_Q(1, 1); BARRIER;                                   \
  } while (0)
#define PHASE4(T, BUF) do {                                                     \
    LOAD_B(BUF, 0);                                                             \
    if ((T) + 2 < NT) { STAGE_A(BUF, (T) + 2, 1);                               \
      asm volatile("s_waitcnt vmcnt(6)" ::: "memory");                          \
    } else { asm volatile("s_waitcnt vmcnt(0)" ::: "memory"); }                 \
    BARRIER; WAITLGKM; MFMA_Q(1, 0); BARRIER;                                   \
  } while (0)

  for (int T = 0; T < NT; T += 2) {
    PHASE1(T, 0); PHASE2(T, 0); PHASE3(T, 0); PHASE4(T, 0);
    PHASE1(T + 1, 1); PHASE2(T + 1, 1); PHASE3(T + 1, 1); PHASE4(T + 1, 1);
  }

  // epilogue: C/D layout col = lane&15 (n), row = (lane>>4)*4 + r (m)
  const int rbase = lk * 4;
  const size_t gr0 = bmBase + wm * 128;
  const int gc0 = (int)bnBase + wn * 64;
#pragma unroll
  for (int mi = 0; mi < 8; ++mi) {
#pragma unroll
    for (int ni = 0; ni < 4; ++ni) {
      int gcol = gc0 + ni * 16 + lm;
      float bv = bias[gcol];
#pragma unroll
      for (int r = 0; r < 4; ++r) {
        size_t grow = gr0 + mi * 16 + rbase + r;
        float v = acc[mi][ni][r] + bv;
        if (EPI == 0) {
          ((u16*)Cout)[grow * ldc + gcol] = f2bf(v);
        } else {
          float gl = 0.5f * v * (1.0f + erff(v * 0.70710678118654752f));
          float y = gl + bf2f(residb[grow * 2048 + gcol]);
          ((float*)Cout)[grow * ldc + gcol] = y;
        }
      }
    }
  }
#undef STAGE_A
#undef STAGE_B
#undef LOAD_A
#undef LOAD_B
#undef MFMA_Q
#undef PHASE1
#undef PHASE2
#undef PHASE3
#undef PHASE4
#undef WAITLGKM
#undef BARRIER
}

// ---------------- fused: sim (MFMA) -> softmax -> retrieved (MFMA) ----------------
__global__ __launch_bounds__(256) void k_mid(const u16* __restrict__ h,
                                             const u16* __restrict__ pb,
                                             const u16* __restrict__ pbT,
                                             u16* __restrict__ comb) {
  __shared__ u16 attn_sm[4][16 * 32];
  const int tid = threadIdx.x;
  const int w = tid >> 6, lane = tid & 63;
  const int lm = lane & 15, lk = lane >> 4;
  const int row0 = blockIdx.x * 64 + w * 16;

  f32x4 zero = {0.f, 0.f, 0.f, 0.f};
  f32x4 acc0 = zero, acc1 = zero;
  float ss = 0.f;

  const u16* hrow = h + ((size_t)(row0 + lm) << 10) + lk * 8;
  const u16* pb0 = pb + (size_t)lm * DD + lk * 8;
  const u16* pb1 = pb + (size_t)(16 + lm) * DD + lk * 8;
#pragma unroll 4
  for (int k0 = 0; k0 < DD; k0 += 32) {
    bf16x8 af = *(const bf16x8*)(hrow + k0);
    bf16x8 b0 = *(const bf16x8*)(pb0 + k0);
    bf16x8 b1 = *(const bf16x8*)(pb1 + k0);
    acc0 = __builtin_amdgcn_mfma_f32_16x16x32_bf16(af, b0, acc0, 0, 0, 0);
    acc1 = __builtin_amdgcn_mfma_f32_16x16x32_bf16(af, b1, acc1, 0, 0, 0);
#pragma unroll
    for (int j = 0; j < 8; ++j) {
      float hv = bf2f((u16)af[j]);
      ss += hv * hv;
    }
  }
  ss += __shfl_xor(ss, 16);
  ss += __shfl_xor(ss, 32);
  float inv = 10.0f / fmaxf(sqrtf(ss), 1e-12f);

  float a0[4], a1[4];
#pragma unroll
  for (int r = 0; r < 4; ++r) {
    float invr = __shfl(inv, lk * 4 + r);
    float s0 = acc0[r] * invr;
    float s1 = acc1[r] * invr;
    float mr = fmaxf(s0, s1);
#pragma unroll
    for (int off = 1; off < 16; off <<= 1) mr = fmaxf(mr, __shfl_xor(mr, off));
    float e0 = expf(s0 - mr);
    float e1 = expf(s1 - mr);
    float sum = e0 + e1;
#pragma unroll
    for (int off = 1; off < 16; off <<= 1) sum += __shfl_xor(sum, off);
    float rs = 1.0f / sum;
    a0[r] = e0 * rs;
    a1[r] = e1 * rs;
  }

  u16* as = attn_sm[w];
#pragma unroll
  for (int r = 0; r < 4; ++r) {
    as[(lk * 4 + r) * 32 + lm] = f2bf(a0[r]);
    as[(lk * 4 + r) * 32 + 16 + lm] = f2bf(a1[r]);
  }
  __syncthreads();
  bf16x8 battn = *(const bf16x8*)(as + lm * 32 + lk * 8);

  u16* crow = comb + ((size_t)(row0 + lm) << 11) + DD;
#pragma unroll 4
  for (int d0 = 0; d0 < DD; d0 += 16) {
    bf16x8 ap = *(const bf16x8*)(pbT + (size_t)(d0 + lm) * PP + lk * 8);
    f32x4 rc = __builtin_amdgcn_mfma_f32_16x16x32_bf16(ap, battn, zero, 0, 0, 0);
    ushort4 o;
    o.x = f2bf(rc[0]); o.y = f2bf(rc[1]); o.z = f2bf(rc[2]); o.w = f2bf(rc[3]);
    *(ushort4*)(crow + d0 + lk * 4) = o;
  }
}

// ---------------- in-place LayerNorm over rows of 1024 ----------------
__global__ __launch_bounds__(256) void k_ln(float* __restrict__ io,
                                            const float* __restrict__ gamma,
                                            const float* __restrict__ beta) {
  __shared__ float sb[8];
  size_t row = blockIdx.x;
  float4* rp = (float4*)(io + (row << 10));
  int tid = threadIdx.x;
  float4 v = rp[tid];
  float s = v.x + v.y + v.z + v.w;
  float q = v.x * v.x + v.y * v.y + v.z * v.z + v.w * v.w;
#pragma unroll
  for (int off = 32; off; off >>= 1) { s += __shfl_xor(s, off); q += __shfl_xor(q, off); }
  if ((tid & 63) == 0) { sb[tid >> 6] = s; sb[4 + (tid >> 6)] = q; }
  __syncthreads();
  s = sb[0] + sb[1] + sb[2] + sb[3];
  q = sb[4] + sb[5] + sb[6] + sb[7];
  float mu = s * (1.f / 1024.f);
  float var = q * (1.f / 1024.f) - mu * mu;
  float rstd = rsqrtf(var + 1e-5f);
  float4 g = ((const float4*)gamma)[tid];
  float4 b = ((const float4*)beta)[tid];
  v.x = (v.x - mu) * rstd * g.x + b.x;
  v.y = (v.y - mu) * rstd * g.y + b.y;
  v.z = (v.z - mu) * rstd * g.z + b.z;
  v.w = (v.w - mu) * rstd * g.w + b.w;
  rp[tid] = v;
}

extern "C" void kernel_launch(void* const* d_in, const int* in_sizes, int n_in,
                              void* d_out, int out_size, void* d_ws, size_t ws_size,
                              hipStream_t stream) {
  const float* x      = (const float*)d_in[0];
  const float* Wi     = (const float*)d_in[1];
  const float* bi     = (const float*)d_in[2];
  const float* Wo     = (const float*)d_in[3];
  const float* bo     = (const float*)d_in[4];
  const float* gamma  = (const float*)d_in[5];
  const float* beta   = (const float*)d_in[6];
  const float* protos = (const float*)d_in[7];
  const int Brows = in_sizes[0] / DD;  // 65536

  u16* comb = (u16*)d_ws;                        // [B, 2048] bf16
  u16* WiB  = comb + (size_t)Brows * 2048;       // [1024, 1024]
  u16* WoB  = WiB + (size_t)1024 * 1024;         // [1024, 2048]
  u16* pb   = WoB + (size_t)1024 * 2048;         // [32, 1024] normalized
  u16* pbT  = pb + (size_t)PP * DD;              // [1024, 32] raw transposed
  u16* hbuf = (u16*)d_out;                       // h bf16 lives in d_out storage

  k_convert_x<<<4096, 256, 0, stream>>>(x, comb, Brows * 256);
  k_convert<<<1024, 256, 0, stream>>>(Wi, WiB, 1024 * 1024 / 4);
  k_convert<<<2048, 256, 0, stream>>>(Wo, WoB, 1024 * 2048 / 4);
  k_proto_prep<<<PP, 256, 0, stream>>>(protos, pb);
  k_protoT<<<(DD * PP + 255) / 256, 256, 0, stream>>>(protos, pbT);

  const int nbn = 1024 / 256;                    // 4 col-blocks
  const int nwg = nbn * (Brows / 256);           // 1024 blocks

  // h = x @ Wi^T + bi
  k_gemm8<0><<<nwg, 512, 0, stream>>>(comb, 2048, WiB, bi, nullptr,
                                      (void*)hbuf, DD, DD, nbn);
  // fused sim -> softmax -> retrieved into combined right half
  k_mid<<<Brows / 64, 256, 0, stream>>>(hbuf, pb, pbT, comb);
  // y = gelu(combined @ Wo^T + bo) + bf16(x)  -> d_out (f32)
  k_gemm8<1><<<nwg, 512, 0, stream>>>(comb, 2048, WoB, bo, comb,
                                      d_out, DD, 2 * DD, nbn);
  // in-place LayerNorm
  k_ln<<<Brows, 256, 0, stream>>>((float*)d_out, gamma, beta);
}

// Round 5
// 898.101 us; speedup vs baseline: 5.7600x; 1.1152x over previous
//
#include <hip/hip_runtime.h>
#include <hip/hip_bf16.h>
#include <math.h>

typedef unsigned short u16;
typedef __attribute__((ext_vector_type(8))) short bf16x8;
typedef __attribute__((ext_vector_type(4))) float f32x4;
typedef __attribute__((address_space(1))) unsigned int gu32;
typedef __attribute__((address_space(3))) unsigned int lu32;

#define DD 1024
#define PP 32

__device__ __forceinline__ u16 f2bf(float f) {
  unsigned u = __float_as_uint(f);
  unsigned r = u + 0x7fffu + ((u >> 16) & 1u);
  return (u16)(r >> 16);
}
__device__ __forceinline__ float bf2f(u16 h) {
  return __uint_as_float(((unsigned)h) << 16);
}

// ---------------- conversions ----------------
__global__ __launch_bounds__(256) void k_convert_x(const float* __restrict__ x,
                                                   u16* __restrict__ comb, int n4) {
  for (int i = blockIdx.x * 256 + threadIdx.x; i < n4; i += gridDim.x * 256) {
    float4 v = ((const float4*)x)[i];
    int row = i >> 8;
    int c4  = i & 255;
    ushort4 o;
    o.x = f2bf(v.x); o.y = f2bf(v.y); o.z = f2bf(v.z); o.w = f2bf(v.w);
    *(ushort4*)(comb + ((size_t)row << 11) + (c4 << 2)) = o;
  }
}

__global__ __launch_bounds__(256) void k_convert(const float* __restrict__ in,
                                                 u16* __restrict__ out, int n4) {
  for (int i = blockIdx.x * 256 + threadIdx.x; i < n4; i += gridDim.x * 256) {
    float4 v = ((const float4*)in)[i];
    ushort4 o;
    o.x = f2bf(v.x); o.y = f2bf(v.y); o.z = f2bf(v.z); o.w = f2bf(v.w);
    ((ushort4*)out)[i] = o;
  }
}

__global__ __launch_bounds__(256) void k_proto_prep(const float* __restrict__ protos,
                                                    u16* __restrict__ pb) {
  __shared__ float sb[4];
  int row = blockIdx.x, tid = threadIdx.x;
  float4 v = ((const float4*)(protos + row * DD))[tid];
  float q = v.x * v.x + v.y * v.y + v.z * v.z + v.w * v.w;
#pragma unroll
  for (int off = 32; off; off >>= 1) q += __shfl_xor(q, off);
  if ((tid & 63) == 0) sb[tid >> 6] = q;
  __syncthreads();
  q = sb[0] + sb[1] + sb[2] + sb[3];
  float inv = 1.0f / fmaxf(sqrtf(q), 1e-12f);
  ushort4 o;
  o.x = f2bf(v.x * inv); o.y = f2bf(v.y * inv); o.z = f2bf(v.z * inv); o.w = f2bf(v.w * inv);
  ((ushort4*)(pb + row * DD))[tid] = o;
}

__global__ __launch_bounds__(256) void k_protoT(const float* __restrict__ protos,
                                                u16* __restrict__ pbT) {
  int i = blockIdx.x * 256 + threadIdx.x;
  if (i < DD * PP) {
    int p = i & 31, d = i >> 5;
    pbT[i] = f2bf(protos[p * DD + d]);
  }
}

// ---------------- 256x256 8-phase bf16 GEMM (B^T layout), T2 LDS swizzle ----------------
// LDS tile is [row][64] u16, linear dest for global_load_lds.
// Swizzle (involution, 16B granularity): chunk' = chunk ^ (row&7). Applied on the
// GLOBAL SOURCE at staging and on the ds_read address — never on the LDS dest.
#define GLL(gsrc, ldst) __builtin_amdgcn_global_load_lds((gu32*)(gsrc), (lu32*)(ldst), 16, 0, 0)

template <int EPI>
__global__ __launch_bounds__(512, 2) void k_gemm8(const u16* __restrict__ A, int lda,
                                                  const u16* __restrict__ Bm,
                                                  const float* __restrict__ bias,
                                                  const u16* __restrict__ residb,
                                                  void* __restrict__ Cout, int ldc,
                                                  int K, int nbn) {
  __shared__ u16 Als[2][256 * 64];
  __shared__ u16 Bls[2][256 * 64];
  const int tid = threadIdx.x;
  const int wid = tid >> 6, lane = tid & 63;
  const int wm = wid >> 2, wn = wid & 3;
  const int lm = lane & 15, lk = lane >> 4;
  const int NT = K >> 6;

  // staging source-column swizzle (u16 units): chunk (lane&7) XOR row-in-group (lane>>3)
  const int scol_sw = (((lane & 7) ^ ((lane >> 3) & 7)) << 3);
  const int srow = lane >> 3;

  // XCD chunked swizzle: blocks sharing an A-tile land on the same XCD, adjacent in time
  int g = blockIdx.x;
  int cpx = gridDim.x >> 3;
  int lin = (g & 7) * cpx + (g >> 3);
  int bn = lin % nbn, bm = lin / nbn;
  const size_t bmBase = (size_t)bm * 256;
  const size_t bnBase = (size_t)bn * 256;

  f32x4 acc[8][4];
#pragma unroll
  for (int i = 0; i < 8; ++i)
#pragma unroll
    for (int j = 0; j < 4; ++j) acc[i][j] = (f32x4){0.f, 0.f, 0.f, 0.f};

  bf16x8 a[4][2], b[2][2];

  // stage one A half (mh): rows {mh*64..+63} and {128+mh*64..+63}, 2 instrs x 8KB
#define STAGE_A(bufv, kt, mh) do {                                              \
    int arow = (mh) * 64 + wid * 8 + srow;                                      \
    int acol = scol_sw + (kt) * 64;                                             \
    GLL(A + (bmBase + arow) * lda + acol, &Als[bufv][((mh) * 64 + wid * 8) * 64]);       \
    GLL(A + (bmBase + 128 + arow) * lda + acol, &Als[bufv][(128 + (mh) * 64 + wid * 8) * 64]); \
  } while (0)

  // stage one B half (nh): n-rows {b*64 + nh*32 .. +31 : b=0..3}, 2 instrs x 8KB
#define STAGE_B(bufv, kt, nh) do {                                              \
    int br0 = ((wid >> 2) << 6) + (nh) * 32 + ((wid & 3) << 3);                 \
    int bcol = scol_sw + (kt) * 64;                                             \
    GLL(Bm + (bnBase + br0 + srow) * (size_t)K + bcol, &Bls[bufv][br0 * 64]);       \
    GLL(Bm + (bnBase + 128 + br0 + srow) * (size_t)K + bcol, &Bls[bufv][(128 + br0) * 64]); \
  } while (0)

  // ds_read with swizzled column: (kk*32 + lk*8) ^ ((lm&7)<<3)
#define LOAD_A(bufv, mh) do {                                                   \
    _Pragma("unroll") for (int mi2 = 0; mi2 < 4; ++mi2) {                       \
      int row = wm * 128 + (mh) * 64 + mi2 * 16 + lm;                           \
      _Pragma("unroll") for (int kk = 0; kk < 2; ++kk)                          \
        a[mi2][kk] = *(const bf16x8*)&Als[bufv][row * 64 + ((kk * 32 + lk * 8) ^ ((lm & 7) << 3))]; \
    }                                                                           \
  } while (0)

#define LOAD_B(bufv, nh) do {                                                   \
    _Pragma("unroll") for (int ni2 = 0; ni2 < 2; ++ni2) {                       \
      int row = wn * 64 + (nh) * 32 + ni2 * 16 + lm;                            \
      _Pragma("unroll") for (int kk = 0; kk < 2; ++kk)                          \
        b[ni2][kk] = *(const bf16x8*)&Bls[bufv][row * 64 + ((kk * 32 + lk * 8) ^ ((lm & 7) << 3))]; \
    }                                                                           \
  } while (0)

#define WAITLGKM do { asm volatile("s_waitcnt lgkmcnt(0)" ::: "memory");        \
    __builtin_amdgcn_sched_barrier(0); } while (0)
#define BARRIER __builtin_amdgcn_s_barrier()

#define MFMA_Q(mh, nh) do {                                                     \
    __builtin_amdgcn_s_setprio(1);                                              \
    _Pragma("unroll") for (int mi2 = 0; mi2 < 4; ++mi2)                         \
    _Pragma("unroll") for (int ni2 = 0; ni2 < 2; ++ni2)                         \
    _Pragma("unroll") for (int kk = 0; kk < 2; ++kk)                            \
      acc[(mh) * 4 + mi2][(nh) * 2 + ni2] = __builtin_amdgcn_mfma_f32_16x16x32_bf16( \
          a[mi2][kk], b[ni2][kk], acc[(mh) * 4 + mi2][(nh) * 2 + ni2], 0, 0, 0); \
    __builtin_amdgcn_s_setprio(0);                                              \
  } while (0)

  // prologue: tile0 fully (4 halves) + tile1 A0,B1,A1 (3 halves) = 14 loads
  STAGE_A(0, 0, 0); STAGE_B(0, 0, 0); STAGE_A(0, 0, 1); STAGE_B(0, 0, 1);
  STAGE_A(1, 1, 0); STAGE_B(1, 1, 1); STAGE_A(1, 1, 1);
  asm volatile("s_waitcnt vmcnt(6)" ::: "memory");  // tile0 complete; 3 halves in flight
  BARRIER;

#define PHASE1(T, BUF) do {                                                     \
    LOAD_A(BUF, 0); LOAD_B(BUF, 0);                                             \
    if ((T) + 1 < NT) STAGE_B(((T) + 1) & 1, (T) + 1, 0);                       \
    BARRIER; WAITLGKM; MFMA_Q(0, 0); BARRIER;                                   \
  } while (0)
#define PHASE2(T, BUF) do {                                                     \
    LOAD_B(BUF, 1);                                                             \
    if ((T) + 2 < NT) STAGE_A(BUF, (T) + 2, 0);                                 \
    BARRIER; WAITLGKM; MFMA_Q(0, 1); BARRIER;                                   \
  } while (0)
#define PHASE3(T, BUF) do {                                                     \
    LOAD_A(BUF, 1);                                                             \
    if ((T) + 2 < NT) STAGE_B(BUF, (T) + 2, 1);                                 \
    BARRIER; WAITLGKM; MFMA_Q(1, 1); BARRIER;                                   \
  } while (0)
#define PHASE4(T, BUF) do {                                                     \
    LOAD_B(BUF, 0);                                                             \
    if ((T) + 2 < NT) { STAGE_A(BUF, (T) + 2, 1);                               \
      asm volatile("s_waitcnt vmcnt(6)" ::: "memory");                          \
    } else { asm volatile("s_waitcnt vmcnt(0)" ::: "memory"); }                 \
    BARRIER; WAITLGKM; MFMA_Q(1, 0); BARRIER;                                   \
  } while (0)

  for (int T = 0; T < NT; T += 2) {
    PHASE1(T, 0); PHASE2(T, 0); PHASE3(T, 0); PHASE4(T, 0);
    PHASE1(T + 1, 1); PHASE2(T + 1, 1); PHASE3(T + 1, 1); PHASE4(T + 1, 1);
  }

  // epilogue: C/D layout col = lane&15 (n), row = (lane>>4)*4 + r (m)
  const int rbase = lk * 4;
  const size_t gr0 = bmBase + wm * 128;
  const int gc0 = (int)bnBase + wn * 64;
#pragma unroll
  for (int mi = 0; mi < 8; ++mi) {
#pragma unroll
    for (int ni = 0; ni < 4; ++ni) {
      int gcol = gc0 + ni * 16 + lm;
      float bv = bias[gcol];
#pragma unroll
      for (int r = 0; r < 4; ++r) {
        size_t grow = gr0 + mi * 16 + rbase + r;
        float v = acc[mi][ni][r] + bv;
        if (EPI == 0) {
          ((u16*)Cout)[grow * ldc + gcol] = f2bf(v);
        } else {
          float gl = 0.5f * v * (1.0f + erff(v * 0.70710678118654752f));
          float y = gl + bf2f(residb[grow * 2048 + gcol]);
          ((float*)Cout)[grow * ldc + gcol] = y;
        }
      }
    }
  }
#undef STAGE_A
#undef STAGE_B
#undef LOAD_A
#undef LOAD_B
#undef MFMA_Q
#undef PHASE1
#undef PHASE2
#undef PHASE3
#undef PHASE4
#undef WAITLGKM
#undef BARRIER
}

// ---------------- fused: sim (MFMA) -> softmax -> retrieved (MFMA) ----------------
__global__ __launch_bounds__(256) void k_mid(const u16* __restrict__ h,
                                             const u16* __restrict__ pb,
                                             const u16* __restrict__ pbT,
                                             u16* __restrict__ comb) {
  __shared__ u16 attn_sm[4][16 * 32];
  const int tid = threadIdx.x;
  const int w = tid >> 6, lane = tid & 63;
  const int lm = lane & 15, lk = lane >> 4;
  const int row0 = blockIdx.x * 64 + w * 16;

  f32x4 zero = {0.f, 0.f, 0.f, 0.f};
  f32x4 acc0 = zero, acc1 = zero;
  float ss = 0.f;

  const u16* hrow = h + ((size_t)(row0 + lm) << 10) + lk * 8;
  const u16* pb0 = pb + (size_t)lm * DD + lk * 8;
  const u16* pb1 = pb + (size_t)(16 + lm) * DD + lk * 8;
#pragma unroll 4
  for (int k0 = 0; k0 < DD; k0 += 32) {
    bf16x8 af = *(const bf16x8*)(hrow + k0);
    bf16x8 b0 = *(const bf16x8*)(pb0 + k0);
    bf16x8 b1 = *(const bf16x8*)(pb1 + k0);
    acc0 = __builtin_amdgcn_mfma_f32_16x16x32_bf16(af, b0, acc0, 0, 0, 0);
    acc1 = __builtin_amdgcn_mfma_f32_16x16x32_bf16(af, b1, acc1, 0, 0, 0);
#pragma unroll
    for (int j = 0; j < 8; ++j) {
      float hv = bf2f((u16)af[j]);
      ss += hv * hv;
    }
  }
  ss += __shfl_xor(ss, 16);
  ss += __shfl_xor(ss, 32);
  float inv = 10.0f / fmaxf(sqrtf(ss), 1e-12f);

  float a0[4], a1[4];
#pragma unroll
  for (int r = 0; r < 4; ++r) {
    float invr = __shfl(inv, lk * 4 + r);
    float s0 = acc0[r] * invr;
    float s1 = acc1[r] * invr;
    float mr = fmaxf(s0, s1);
#pragma unroll
    for (int off = 1; off < 16; off <<= 1) mr = fmaxf(mr, __shfl_xor(mr, off));
    float e0 = expf(s0 - mr);
    float e1 = expf(s1 - mr);
    float sum = e0 + e1;
#pragma unroll
    for (int off = 1; off < 16; off <<= 1) sum += __shfl_xor(sum, off);
    float rs = 1.0f / sum;
    a0[r] = e0 * rs;
    a1[r] = e1 * rs;
  }

  u16* as = attn_sm[w];
#pragma unroll
  for (int r = 0; r < 4; ++r) {
    as[(lk * 4 + r) * 32 + lm] = f2bf(a0[r]);
    as[(lk * 4 + r) * 32 + 16 + lm] = f2bf(a1[r]);
  }
  __syncthreads();
  bf16x8 battn = *(const bf16x8*)(as + lm * 32 + lk * 8);

  u16* crow = comb + ((size_t)(row0 + lm) << 11) + DD;
#pragma unroll 4
  for (int d0 = 0; d0 < DD; d0 += 16) {
    bf16x8 ap = *(const bf16x8*)(pbT + (size_t)(d0 + lm) * PP + lk * 8);
    f32x4 rc = __builtin_amdgcn_mfma_f32_16x16x32_bf16(ap, battn, zero, 0, 0, 0);
    ushort4 o;
    o.x = f2bf(rc[0]); o.y = f2bf(rc[1]); o.z = f2bf(rc[2]); o.w = f2bf(rc[3]);
    *(ushort4*)(crow + d0 + lk * 4) = o;
  }
}

// ---------------- in-place LayerNorm over rows of 1024 ----------------
__global__ __launch_bounds__(256) void k_ln(float* __restrict__ io,
                                            const float* __restrict__ gamma,
                                            const float* __restrict__ beta) {
  __shared__ float sb[8];
  size_t row = blockIdx.x;
  float4* rp = (float4*)(io + (row << 10));
  int tid = threadIdx.x;
  float4 v = rp[tid];
  float s = v.x + v.y + v.z + v.w;
  float q = v.x * v.x + v.y * v.y + v.z * v.z + v.w * v.w;
#pragma unroll
  for (int off = 32; off; off >>= 1) { s += __shfl_xor(s, off); q += __shfl_xor(q, off); }
  if ((tid & 63) == 0) { sb[tid >> 6] = s; sb[4 + (tid >> 6)] = q; }
  __syncthreads();
  s = sb[0] + sb[1] + sb[2] + sb[3];
  q = sb[4] + sb[5] + sb[6] + sb[7];
  float mu = s * (1.f / 1024.f);
  float var = q * (1.f / 1024.f) - mu * mu;
  float rstd = rsqrtf(var + 1e-5f);
  float4 g = ((const float4*)gamma)[tid];
  float4 b = ((const float4*)beta)[tid];
  v.x = (v.x - mu) * rstd * g.x + b.x;
  v.y = (v.y - mu) * rstd * g.y + b.y;
  v.z = (v.z - mu) * rstd * g.z + b.z;
  v.w = (v.w - mu) * rstd * g.w + b.w;
  rp[tid] = v;
}

extern "C" void kernel_launch(void* const* d_in, const int* in_sizes, int n_in,
                              void* d_out, int out_size, void* d_ws, size_t ws_size,
                              hipStream_t stream) {
  const float* x      = (const float*)d_in[0];
  const float* Wi     = (const float*)d_in[1];
  const float* bi     = (const float*)d_in[2];
  const float* Wo     = (const float*)d_in[3];
  const float* bo     = (const float*)d_in[4];
  const float* gamma  = (const float*)d_in[5];
  const float* beta   = (const float*)d_in[6];
  const float* protos = (const float*)d_in[7];
  const int Brows = in_sizes[0] / DD;  // 65536

  u16* comb = (u16*)d_ws;                        // [B, 2048] bf16
  u16* WiB  = comb + (size_t)Brows * 2048;       // [1024, 1024]
  u16* WoB  = WiB + (size_t)1024 * 1024;         // [1024, 2048]
  u16* pb   = WoB + (size_t)1024 * 2048;         // [32, 1024] normalized
  u16* pbT  = pb + (size_t)PP * DD;              // [1024, 32] raw transposed
  u16* hbuf = (u16*)d_out;                       // h bf16 lives in d_out storage

  k_convert_x<<<4096, 256, 0, stream>>>(x, comb, Brows * 256);
  k_convert<<<1024, 256, 0, stream>>>(Wi, WiB, 1024 * 1024 / 4);
  k_convert<<<2048, 256, 0, stream>>>(Wo, WoB, 1024 * 2048 / 4);
  k_proto_prep<<<PP, 256, 0, stream>>>(protos, pb);
  k_protoT<<<(DD * PP + 255) / 256, 256, 0, stream>>>(protos, pbT);

  const int nbn = 1024 / 256;                    // 4 col-blocks
  const int nwg = nbn * (Brows / 256);           // 1024 blocks

  // h = x @ Wi^T + bi
  k_gemm8<0><<<nwg, 512, 0, stream>>>(comb, 2048, WiB, bi, nullptr,
                                      (void*)hbuf, DD, DD, nbn);
  // fused sim -> softmax -> retrieved into combined right half
  k_mid<<<Brows / 64, 256, 0, stream>>>(hbuf, pb, pbT, comb);
  // y = gelu(combined @ Wo^T + bo) + bf16(x)  -> d_out (f32)
  k_gemm8<1><<<nwg, 512, 0, stream>>>(comb, 2048, WoB, bo, comb,
                                      d_out, DD, 2 * DD, nbn);
  // in-place LayerNorm
  k_ln<<<Brows, 256, 0, stream>>>((float*)d_out, gamma, beta);
}

// Round 6
// 871.514 us; speedup vs baseline: 5.9357x; 1.0305x over previous
//
#include <hip/hip_runtime.h>
#include <hip/hip_bf16.h>
#include <math.h>

typedef unsigned short u16;
typedef __attribute__((ext_vector_type(8))) short bf16x8;
typedef __attribute__((ext_vector_type(4))) float f32x4;
typedef __attribute__((address_space(1))) unsigned int gu32;
typedef __attribute__((address_space(3))) unsigned int lu32;

#define DD 1024
#define PP 32

__device__ __forceinline__ u16 f2bf(float f) {
  unsigned u = __float_as_uint(f);
  unsigned r = u + 0x7fffu + ((u >> 16) & 1u);
  return (u16)(r >> 16);
}
__device__ __forceinline__ float bf2f(u16 h) {
  return __uint_as_float(((unsigned)h) << 16);
}

// ---------------- conversions ----------------
__global__ __launch_bounds__(256) void k_convert_x(const float* __restrict__ x,
                                                   u16* __restrict__ comb, int n4) {
  for (int i = blockIdx.x * 256 + threadIdx.x; i < n4; i += gridDim.x * 256) {
    float4 v = ((const float4*)x)[i];
    int row = i >> 8;
    int c4  = i & 255;
    ushort4 o;
    o.x = f2bf(v.x); o.y = f2bf(v.y); o.z = f2bf(v.z); o.w = f2bf(v.w);
    *(ushort4*)(comb + ((size_t)row << 11) + (c4 << 2)) = o;
  }
}

__global__ __launch_bounds__(256) void k_convert(const float* __restrict__ in,
                                                 u16* __restrict__ out, int n4) {
  for (int i = blockIdx.x * 256 + threadIdx.x; i < n4; i += gridDim.x * 256) {
    float4 v = ((const float4*)in)[i];
    ushort4 o;
    o.x = f2bf(v.x); o.y = f2bf(v.y); o.z = f2bf(v.z); o.w = f2bf(v.w);
    ((ushort4*)out)[i] = o;
  }
}

__global__ __launch_bounds__(256) void k_proto_prep(const float* __restrict__ protos,
                                                    u16* __restrict__ pb) {
  __shared__ float sb[4];
  int row = blockIdx.x, tid = threadIdx.x;
  float4 v = ((const float4*)(protos + row * DD))[tid];
  float q = v.x * v.x + v.y * v.y + v.z * v.z + v.w * v.w;
#pragma unroll
  for (int off = 32; off; off >>= 1) q += __shfl_xor(q, off);
  if ((tid & 63) == 0) sb[tid >> 6] = q;
  __syncthreads();
  q = sb[0] + sb[1] + sb[2] + sb[3];
  float inv = 1.0f / fmaxf(sqrtf(q), 1e-12f);
  ushort4 o;
  o.x = f2bf(v.x * inv); o.y = f2bf(v.y * inv); o.z = f2bf(v.z * inv); o.w = f2bf(v.w * inv);
  ((ushort4*)(pb + row * DD))[tid] = o;
}

__global__ __launch_bounds__(256) void k_protoT(const float* __restrict__ protos,
                                                u16* __restrict__ pbT) {
  int i = blockIdx.x * 256 + threadIdx.x;
  if (i < DD * PP) {
    int p = i & 31, d = i >> 5;
    pbT[i] = f2bf(protos[p * DD + d]);
  }
}

// ---------------- 256x256 8-phase bf16 GEMM (B^T layout), T2 LDS swizzle ----------------
// LDS tile [row][64] u16 linear dest; swizzle chunk' = chunk ^ (row&7) applied on the
// global SOURCE at staging and on the ds_read address. No explicit lgkm drains:
// compiler emits fine-grained lgkmcnt so MFMA overlaps the LDS transfer.
#define GLL(gsrc, ldst) __builtin_amdgcn_global_load_lds((gu32*)(gsrc), (lu32*)(ldst), 16, 0, 0)

template <int EPI>
__global__ __launch_bounds__(512, 2) void k_gemm8(const u16* __restrict__ A, int lda,
                                                  const u16* __restrict__ Bm,
                                                  const float* __restrict__ bias,
                                                  const u16* __restrict__ residb,
                                                  void* __restrict__ Cout, int ldc,
                                                  int K, int nbn) {
  __shared__ u16 Als[2][256 * 64];
  __shared__ u16 Bls[2][256 * 64];
  const int tid = threadIdx.x;
  const int wid = tid >> 6, lane = tid & 63;
  const int wm = wid >> 2, wn = wid & 3;
  const int lm = lane & 15, lk = lane >> 4;
  const int NT = K >> 6;

  const int scol_sw = (((lane & 7) ^ ((lane >> 3) & 7)) << 3);
  const int srow = lane >> 3;

  // XCD chunked swizzle
  int g = blockIdx.x;
  int cpx = gridDim.x >> 3;
  int lin = (g & 7) * cpx + (g >> 3);
  int bn = lin % nbn, bm = lin / nbn;
  const size_t bmBase = (size_t)bm * 256;
  const size_t bnBase = (size_t)bn * 256;

  f32x4 acc[8][4];
#pragma unroll
  for (int i = 0; i < 8; ++i)
#pragma unroll
    for (int j = 0; j < 4; ++j) acc[i][j] = (f32x4){0.f, 0.f, 0.f, 0.f};

  bf16x8 a[4][2], b0[2][2], b1[2][2];

#define STAGE_A(bufv, kt, mh) do {                                              \
    int arow = (mh) * 64 + wid * 8 + srow;                                      \
    int acol = scol_sw + (kt) * 64;                                             \
    GLL(A + (bmBase + arow) * lda + acol, &Als[bufv][((mh) * 64 + wid * 8) * 64]);       \
    GLL(A + (bmBase + 128 + arow) * lda + acol, &Als[bufv][(128 + (mh) * 64 + wid * 8) * 64]); \
  } while (0)

#define STAGE_B(bufv, kt, nh) do {                                              \
    int br0 = ((wid >> 2) << 6) + (nh) * 32 + ((wid & 3) << 3);                 \
    int bcol = scol_sw + (kt) * 64;                                             \
    GLL(Bm + (bnBase + br0 + srow) * (size_t)K + bcol, &Bls[bufv][br0 * 64]);       \
    GLL(Bm + (bnBase + 128 + br0 + srow) * (size_t)K + bcol, &Bls[bufv][(128 + br0) * 64]); \
  } while (0)

#define LOAD_A(bufv, mh) do {                                                   \
    _Pragma("unroll") for (int mi2 = 0; mi2 < 4; ++mi2) {                       \
      int row = wm * 128 + (mh) * 64 + mi2 * 16 + lm;                           \
      _Pragma("unroll") for (int kk = 0; kk < 2; ++kk)                          \
        a[mi2][kk] = *(const bf16x8*)&Als[bufv][row * 64 + ((kk * 32 + lk * 8) ^ ((lm & 7) << 3))]; \
    }                                                                           \
  } while (0)

#define LOAD_B(dst, bufv, nh) do {                                              \
    _Pragma("unroll") for (int ni2 = 0; ni2 < 2; ++ni2) {                       \
      int row = wn * 64 + (nh) * 32 + ni2 * 16 + lm;                            \
      _Pragma("unroll") for (int kk = 0; kk < 2; ++kk)                          \
        dst[ni2][kk] = *(const bf16x8*)&Bls[bufv][row * 64 + ((kk * 32 + lk * 8) ^ ((lm & 7) << 3))]; \
    }                                                                           \
  } while (0)

  // raw barrier + compiler-level memory fence (prevents hoisting ds_read/STAGE
  // across the cross-wave sync point; HW waitcnts stay compiler-fine-grained)
#define BARRIER do { __builtin_amdgcn_s_barrier(); asm volatile("" ::: "memory"); } while (0)

#define MFMA_Q(bb, mh, nh) do {                                                 \
    __builtin_amdgcn_s_setprio(1);                                              \
    _Pragma("unroll") for (int mi2 = 0; mi2 < 4; ++mi2)                         \
    _Pragma("unroll") for (int ni2 = 0; ni2 < 2; ++ni2)                         \
    _Pragma("unroll") for (int kk = 0; kk < 2; ++kk)                            \
      acc[(mh) * 4 + mi2][(nh) * 2 + ni2] = __builtin_amdgcn_mfma_f32_16x16x32_bf16( \
          a[mi2][kk], bb[ni2][kk], acc[(mh) * 4 + mi2][(nh) * 2 + ni2], 0, 0, 0); \
    __builtin_amdgcn_s_setprio(0);                                              \
  } while (0)

  // prologue: tile0 fully + tile1 A0,B1,A1 (B0 of tile1 staged by PHASE1(0))
  STAGE_A(0, 0, 0); STAGE_B(0, 0, 0); STAGE_A(0, 0, 1); STAGE_B(0, 0, 1);
  STAGE_A(1, 1, 0); STAGE_B(1, 1, 1); STAGE_A(1, 1, 1);
  asm volatile("s_waitcnt vmcnt(6)" ::: "memory");  // tile0 complete; 3 halves in flight
  BARRIER;

#define PHASE1(T, BUF) do {                                                     \
    LOAD_A(BUF, 0); LOAD_B(b0, BUF, 0);                                         \
    if ((T) + 1 < NT) STAGE_B(((T) + 1) & 1, (T) + 1, 0);                       \
    BARRIER; MFMA_Q(b0, 0, 0); BARRIER;                                         \
  } while (0)
#define PHASE2(T, BUF) do {                                                     \
    LOAD_B(b1, BUF, 1);                                                         \
    if ((T) + 2 < NT) STAGE_A(BUF, (T) + 2, 0);                                 \
    BARRIER; MFMA_Q(b1, 0, 1); BARRIER;                                         \
  } while (0)
#define PHASE3(T, BUF) do {                                                     \
    LOAD_A(BUF, 1);                                                             \
    if ((T) + 2 < NT) STAGE_B(BUF, (T) + 2, 1);                                 \
    BARRIER; MFMA_Q(b1, 1, 1); BARRIER;                                         \
  } while (0)
#define PHASE4(T, BUF) do {                                                     \
    if ((T) + 2 < NT) { STAGE_A(BUF, (T) + 2, 1);                               \
      asm volatile("s_waitcnt vmcnt(6)" ::: "memory");                          \
    } else { asm volatile("s_waitcnt vmcnt(0)" ::: "memory"); }                 \
    BARRIER; MFMA_Q(b0, 1, 0); BARRIER;                                         \
  } while (0)

  for (int T = 0; T < NT; T += 2) {
    PHASE1(T, 0); PHASE2(T, 0); PHASE3(T, 0); PHASE4(T, 0);
    PHASE1(T + 1, 1); PHASE2(T + 1, 1); PHASE3(T + 1, 1); PHASE4(T + 1, 1);
  }

  // epilogue: C/D layout col = lane&15 (n), row = (lane>>4)*4 + r (m)
  const int rbase = lk * 4;
  const size_t gr0 = bmBase + wm * 128;
  const int gc0 = (int)bnBase + wn * 64;
#pragma unroll
  for (int mi = 0; mi < 8; ++mi) {
#pragma unroll
    for (int ni = 0; ni < 4; ++ni) {
      int gcol = gc0 + ni * 16 + lm;
      float bv = bias[gcol];
#pragma unroll
      for (int r = 0; r < 4; ++r) {
        size_t grow = gr0 + mi * 16 + rbase + r;
        float v = acc[mi][ni][r] + bv;
        if (EPI == 0) {
          ((u16*)Cout)[grow * ldc + gcol] = f2bf(v);
        } else {
          float gl = 0.5f * v * (1.0f + erff(v * 0.70710678118654752f));
          float y = gl + bf2f(residb[grow * 2048 + gcol]);
          ((float*)Cout)[grow * ldc + gcol] = y;
        }
      }
    }
  }
#undef STAGE_A
#undef STAGE_B
#undef LOAD_A
#undef LOAD_B
#undef MFMA_Q
#undef PHASE1
#undef PHASE2
#undef PHASE3
#undef PHASE4
#undef BARRIER
}

// ---------------- fused: sim (MFMA) -> softmax -> retrieved (MFMA) ----------------
__global__ __launch_bounds__(256) void k_mid(const u16* __restrict__ h,
                                             const u16* __restrict__ pb,
                                             const u16* __restrict__ pbT,
                                             u16* __restrict__ comb) {
  __shared__ u16 attn_sm[4][16 * 32];
  const int tid = threadIdx.x;
  const int w = tid >> 6, lane = tid & 63;
  const int lm = lane & 15, lk = lane >> 4;
  const int row0 = blockIdx.x * 64 + w * 16;

  f32x4 zero = {0.f, 0.f, 0.f, 0.f};
  f32x4 acc0 = zero, acc1 = zero;
  float ss = 0.f;

  const u16* hrow = h + ((size_t)(row0 + lm) << 10) + lk * 8;
  const u16* pb0 = pb + (size_t)lm * DD + lk * 8;
  const u16* pb1 = pb + (size_t)(16 + lm) * DD + lk * 8;
#pragma unroll 4
  for (int k0 = 0; k0 < DD; k0 += 32) {
    bf16x8 af = *(const bf16x8*)(hrow + k0);
    bf16x8 b0 = *(const bf16x8*)(pb0 + k0);
    bf16x8 b1 = *(const bf16x8*)(pb1 + k0);
    acc0 = __builtin_amdgcn_mfma_f32_16x16x32_bf16(af, b0, acc0, 0, 0, 0);
    acc1 = __builtin_amdgcn_mfma_f32_16x16x32_bf16(af, b1, acc1, 0, 0, 0);
#pragma unroll
    for (int j = 0; j < 8; ++j) {
      float hv = bf2f((u16)af[j]);
      ss += hv * hv;
    }
  }
  ss += __shfl_xor(ss, 16);
  ss += __shfl_xor(ss, 32);
  float inv = 10.0f / fmaxf(sqrtf(ss), 1e-12f);

  float a0[4], a1[4];
#pragma unroll
  for (int r = 0; r < 4; ++r) {
    float invr = __shfl(inv, lk * 4 + r);
    float s0 = acc0[r] * invr;
    float s1 = acc1[r] * invr;
    float mr = fmaxf(s0, s1);
#pragma unroll
    for (int off = 1; off < 16; off <<= 1) mr = fmaxf(mr, __shfl_xor(mr, off));
    float e0 = expf(s0 - mr);
    float e1 = expf(s1 - mr);
    float sum = e0 + e1;
#pragma unroll
    for (int off = 1; off < 16; off <<= 1) sum += __shfl_xor(sum, off);
    float rs = 1.0f / sum;
    a0[r] = e0 * rs;
    a1[r] = e1 * rs;
  }

  u16* as = attn_sm[w];
#pragma unroll
  for (int r = 0; r < 4; ++r) {
    as[(lk * 4 + r) * 32 + lm] = f2bf(a0[r]);
    as[(lk * 4 + r) * 32 + 16 + lm] = f2bf(a1[r]);
  }
  __syncthreads();
  bf16x8 battn = *(const bf16x8*)(as + lm * 32 + lk * 8);

  u16* crow = comb + ((size_t)(row0 + lm) << 11) + DD;
#pragma unroll 4
  for (int d0 = 0; d0 < DD; d0 += 16) {
    bf16x8 ap = *(const bf16x8*)(pbT + (size_t)(d0 + lm) * PP + lk * 8);
    f32x4 rc = __builtin_amdgcn_mfma_f32_16x16x32_bf16(ap, battn, zero, 0, 0, 0);
    ushort4 o;
    o.x = f2bf(rc[0]); o.y = f2bf(rc[1]); o.z = f2bf(rc[2]); o.w = f2bf(rc[3]);
    *(ushort4*)(crow + d0 + lk * 4) = o;
  }
}

// ---------------- in-place LayerNorm over rows of 1024 ----------------
__global__ __launch_bounds__(256) void k_ln(float* __restrict__ io,
                                            const float* __restrict__ gamma,
                                            const float* __restrict__ beta) {
  __shared__ float sb[8];
  size_t row = blockIdx.x;
  float4* rp = (float4*)(io + (row << 10));
  int tid = threadIdx.x;
  float4 v = rp[tid];
  float s = v.x + v.y + v.z + v.w;
  float q = v.x * v.x + v.y * v.y + v.z * v.z + v.w * v.w;
#pragma unroll
  for (int off = 32; off; off >>= 1) { s += __shfl_xor(s, off); q += __shfl_xor(q, off); }
  if ((tid & 63) == 0) { sb[tid >> 6] = s; sb[4 + (tid >> 6)] = q; }
  __syncthreads();
  s = sb[0] + sb[1] + sb[2] + sb[3];
  q = sb[4] + sb[5] + sb[6] + sb[7];
  float mu = s * (1.f / 1024.f);
  float var = q * (1.f / 1024.f) - mu * mu;
  float rstd = rsqrtf(var + 1e-5f);
  float4 g = ((const float4*)gamma)[tid];
  float4 b = ((const float4*)beta)[tid];
  v.x = (v.x - mu) * rstd * g.x + b.x;
  v.y = (v.y - mu) * rstd * g.y + b.y;
  v.z = (v.z - mu) * rstd * g.z + b.z;
  v.w = (v.w - mu) * rstd * g.w + b.w;
  rp[tid] = v;
}

extern "C" void kernel_launch(void* const* d_in, const int* in_sizes, int n_in,
                              void* d_out, int out_size, void* d_ws, size_t ws_size,
                              hipStream_t stream) {
  const float* x      = (const float*)d_in[0];
  const float* Wi     = (const float*)d_in[1];
  const float* bi     = (const float*)d_in[2];
  const float* Wo     = (const float*)d_in[3];
  const float* bo     = (const float*)d_in[4];
  const float* gamma  = (const float*)d_in[5];
  const float* beta   = (const float*)d_in[6];
  const float* protos = (const float*)d_in[7];
  const int Brows = in_sizes[0] / DD;  // 65536

  u16* comb = (u16*)d_ws;                        // [B, 2048] bf16
  u16* WiB  = comb + (size_t)Brows * 2048;       // [1024, 1024]
  u16* WoB  = WiB + (size_t)1024 * 1024;         // [1024, 2048]
  u16* pb   = WoB + (size_t)1024 * 2048;         // [32, 1024] normalized
  u16* pbT  = pb + (size_t)PP * DD;              // [1024, 32] raw transposed
  u16* hbuf = (u16*)d_out;                       // h bf16 lives in d_out storage

  k_convert_x<<<4096, 256, 0, stream>>>(x, comb, Brows * 256);
  k_convert<<<1024, 256, 0, stream>>>(Wi, WiB, 1024 * 1024 / 4);
  k_convert<<<2048, 256, 0, stream>>>(Wo, WoB, 1024 * 2048 / 4);
  k_proto_prep<<<PP, 256, 0, stream>>>(protos, pb);
  k_protoT<<<(DD * PP + 255) / 256, 256, 0, stream>>>(protos, pbT);

  const int nbn = 1024 / 256;                    // 4 col-blocks
  const int nwg = nbn * (Brows / 256);           // 1024 blocks

  // h = x @ Wi^T + bi
  k_gemm8<0><<<nwg, 512, 0, stream>>>(comb, 2048, WiB, bi, nullptr,
                                      (void*)hbuf, DD, DD, nbn);
  // fused sim -> softmax -> retrieved into combined right half
  k_mid<<<Brows / 64, 256, 0, stream>>>(hbuf, pb, pbT, comb);
  // y = gelu(combined @ Wo^T + bo) + bf16(x)  -> d_out (f32)
  k_gemm8<1><<<nwg, 512, 0, stream>>>(comb, 2048, WoB, bo, comb,
                                      d_out, DD, 2 * DD, nbn);
  // in-place LayerNorm
  k_ln<<<Brows, 256, 0, stream>>>((float*)d_out, gamma, beta);
}